// Round 4
// baseline (74.199 us; speedup 1.0000x reference)
//
#include <hip/hip_runtime.h>
#include <hip/hip_bf16.h>

// TextEncoder: segment-mean pool -> relu(x@W1+b1) -> relu(h@W2+b2) -> LayerNorm
// R4: single fused MLP kernel. Per 512-thread block (8 waves), 64 output rows:
//   phase 1: GEMM1 (K=768) in two BN=256 halves, h1 = relu(.) written to LDS
//   phase 2: GEMM2 (K=512) A-operand straight from LDS h1, + bias/relu/LN
// h1 never goes to HBM. Staging LDS (20KB x2 dbuf) time-shared across phases.
//
// Padding: W1T=[512][768] (rows>=500 zero) -> h1 pad cols = relu(0)=0;
// W2T=[320][512] (k>=500, n>=300 zero) -> pad out cols = 0, excluded from LN.

#define N_  64
#define L_  514
#define D_  768
#define W_  256
#define H1_ 500
#define H1P 512
#define H2_ 300
#define H2P 320
#define LN_EPS 1e-5f
#define M_  (N_ * W_)   // 16384

typedef __bf16 bf16x8 __attribute__((ext_vector_type(8)));
typedef float  f32x4  __attribute__((ext_vector_type(4)));

__device__ __forceinline__ void load_lds16(const void* g, void* l) {
    __builtin_amdgcn_global_load_lds(
        (const __attribute__((address_space(1))) void*)g,
        (__attribute__((address_space(3))) void*)l, 16, 0, 0);
}

// ------------------------------------------------------------------ prep ---
#define CONV1_ELEMS (H1P * D_)     // 393216
#define CONV2_ELEMS (H2P * H1P)    // 163840
#define CONV1_B ((CONV1_ELEMS + 191) / 192)   // 2048
#define CONV2_B ((CONV2_ELEMS + 191) / 192)   // 854

__global__ __launch_bounds__(192) void prep_kernel(
    const float* __restrict__ texts, const int* __restrict__ wstart,
    const int* __restrict__ wend, const int* __restrict__ wlen,
    const float* __restrict__ W1, const float* __restrict__ W2,
    __hip_bfloat16* __restrict__ pooled, __hip_bfloat16* __restrict__ W1T,
    __hip_bfloat16* __restrict__ W2T)
{
    int b = blockIdx.x;
    if (b < M_) {
        int n = b >> 8;
        int w = b & (W_ - 1);
        int s = wstart[b], e = wend[b];
        bool live = (w < wlen[n]);
        int d = threadIdx.x * 4;
        float4 acc = make_float4(0.f, 0.f, 0.f, 0.f);
        if (live) {
            const float* base = texts + ((size_t)n * L_ + 1) * D_ + d;  // tok=texts[:,1:-1]
            for (int i = s; i < e; ++i) {
                float4 v = *reinterpret_cast<const float4*>(base + (size_t)i * D_);
                acc.x += v.x; acc.y += v.y; acc.z += v.z; acc.w += v.w;
            }
            float inv = 1.0f / (float)max(e - s, 1);
            acc.x *= inv; acc.y *= inv; acc.z *= inv; acc.w *= inv;
        }
        union { __hip_bfloat16 h[4]; uint2 u; } o;
        o.h[0] = __float2bfloat16(acc.x); o.h[1] = __float2bfloat16(acc.y);
        o.h[2] = __float2bfloat16(acc.z); o.h[3] = __float2bfloat16(acc.w);
        *reinterpret_cast<uint2*>(pooled + (size_t)b * D_ + d) = o.u;
    } else if (b < M_ + CONV1_B) {
        int t = (b - M_) * 192 + threadIdx.x;
        if (t < CONV1_ELEMS) {
            int n = t / D_, k = t - n * D_;
            float v = (n < H1_) ? W1[(size_t)k * H1_ + n] : 0.f;
            W1T[t] = __float2bfloat16(v);
        }
    } else {
        int t = (b - M_ - CONV1_B) * 192 + threadIdx.x;
        if (t < CONV2_ELEMS) {
            int n = t >> 9, k = t & (H1P - 1);
            float v = (n < H2_ && k < H1_) ? W2[(size_t)k * H2_ + n] : 0.f;
            W2T[t] = __float2bfloat16(v);
        }
    }
}

// ---------------------------------------------------- fused MLP + LN -------
// 512 thr = 8 waves. Block owns rows [bm, bm+64).
// Phase 1 wave grid 2x4: wave tile 32x64 (FM=2, FN=4), two N-halves of 256.
// Phase 2 wave grid 2x4: wave tile 32x80 (FM=2, FN=5), BN=320, K=512.
__global__ __launch_bounds__(512, 1) void mlp_ln_kernel(
    const ushort* __restrict__ A, const ushort* __restrict__ W1T,
    const ushort* __restrict__ W2T, const float* __restrict__ b1,
    const float* __restrict__ b2, const float* __restrict__ gamma,
    const float* __restrict__ beta, float* __restrict__ out)
{
    __shared__ __align__(16) char stg[2 * 20480];   // dbuf staging, both phases
    __shared__ __align__(16) char h1l[64 * 1024];   // h1 tile 64 x 512 bf16
    __shared__ float red[2][32][4][2];              // [wm][row][wn][sum|sq]

    const int tid  = threadIdx.x;
    const int wave = tid >> 6, lane = tid & 63;
    const int wm = wave >> 2, wn = wave & 3;        // 2 x 4 (both phases)
    const int bm = blockIdx.x * 64;
    const int lrow = lane >> 2, lslot = lane & 3;
    const int g = lane >> 4, fr = lane & 15;

    // ---- staging lambdas (linear LDS dest + swizzled global source, #21) ----
    auto stage1 = [&](int buf, int ss) {            // ss in [0,48): half=ss/24
        char* base = stg + buf * 20480;
        int nh = (ss >= 24);
        int kt = (ss - nh * 24) * 32;
        #pragma unroll
        for (int c0 = 0; c0 < 3; ++c0) {
            int c = wave + c0 * 8;
            if (c >= 20) break;
            int row, off; const ushort* src;
            if (c < 4) { row = c * 16 + lrow;
                         src = A + (size_t)(bm + row) * D_; off = c * 1024; }
            else { int cc = c - 4; row = cc * 16 + lrow;
                   src = W1T + (size_t)(nh * 256 + row) * D_; off = 4096 + cc * 1024; }
            int sslot = lslot ^ ((row >> 1) & 3);
            load_lds16(src + kt + sslot * 8, base + off);
        }
    };
    auto stage2 = [&](int buf, int kt) {            // W2T tile: 320 rows x 64B
        char* base = stg + buf * 20480;
        #pragma unroll
        for (int c0 = 0; c0 < 3; ++c0) {
            int c = wave + c0 * 8;
            if (c >= 20) break;
            int row = c * 16 + lrow;
            int sslot = lslot ^ ((row >> 1) & 3);
            load_lds16(W2T + (size_t)row * H1P + kt + sslot * 8, base + c * 1024);
        }
    };

    // =========================== phase 1: GEMM1 =============================
    f32x4 acc[2][4] = {};

    auto epi1 = [&](int nh) {   // relu(acc + b1) -> h1l (swizzled), then zero acc
        #pragma unroll
        for (int mi = 0; mi < 2; ++mi)
            #pragma unroll
            for (int ni = 0; ni < 4; ++ni) {
                int col = nh * 256 + wn * 64 + ni * 16 + fr;
                float bv = (col < H1_) ? b1[col] : 0.f;
                #pragma unroll
                for (int j = 0; j < 4; ++j) {
                    int row = wm * 32 + mi * 16 + g * 4 + j;
                    float v = acc[mi][ni][j] + bv;
                    v = v > 0.f ? v : 0.f;
                    *(ushort*)(h1l + row * 1024 + (((col >> 3) ^ (row & 7)) << 4)
                               + (col & 7) * 2) =
                        __hip_bfloat16_raw(__float2bfloat16(v)).x;
                    acc[mi][ni][j] = 0.f;
                }
            }
    };

    stage1(0, 0);
    __syncthreads();
    int cur = 0;
    for (int ss = 0; ss < 48; ++ss) {
        if (ss + 1 < 48) stage1(cur ^ 1, ss + 1);
        else             stage2(cur ^ 1, 0);        // issue-early phase-2 buf0
        const char* base = stg + cur * 20480;
        bf16x8 af[2], bf[4];
        #pragma unroll
        for (int mi = 0; mi < 2; ++mi) {
            int r = wm * 32 + mi * 16 + fr;
            af[mi] = *(const bf16x8*)(base + r * 64 + ((g ^ ((r >> 1) & 3)) << 4));
        }
        #pragma unroll
        for (int ni = 0; ni < 4; ++ni) {
            int r = wn * 64 + ni * 16 + fr;
            bf[ni] = *(const bf16x8*)(base + 4096 + r * 64 + ((g ^ ((r >> 1) & 3)) << 4));
        }
        #pragma unroll
        for (int mi = 0; mi < 2; ++mi)
            #pragma unroll
            for (int ni = 0; ni < 4; ++ni)
                acc[mi][ni] = __builtin_amdgcn_mfma_f32_16x16x32_bf16(
                    af[mi], bf[ni], acc[mi][ni], 0, 0, 0);
        if (ss == 23) epi1(0);
        __syncthreads();
        cur ^= 1;
    }
    epi1(1);
    __syncthreads();    // h1l complete + stage2 buf0 drained (vmcnt 0 at barrier)

    // =========================== phase 2: GEMM2 =============================
    f32x4 acc2[2][5] = {};
    int cur2 = 0;       // buf0 = stg[0] (staged at ss==47: cur^1 == 0)
    for (int t = 0; t < 16; ++t) {
        if (t + 1 < 16) stage2(cur2 ^ 1, (t + 1) * 32);
        const char* base = stg + cur2 * 20480;
        bf16x8 af[2], bf[5];
        #pragma unroll
        for (int mi = 0; mi < 2; ++mi) {
            int r = wm * 32 + mi * 16 + fr;
            af[mi] = *(const bf16x8*)(h1l + r * 1024 + ((((t * 4 + g) ^ (r & 7)) << 4)));
        }
        #pragma unroll
        for (int ni = 0; ni < 5; ++ni) {
            int r = wn * 80 + ni * 16 + fr;
            bf[ni] = *(const bf16x8*)(base + r * 64 + ((g ^ ((r >> 1) & 3)) << 4));
        }
        #pragma unroll
        for (int mi = 0; mi < 2; ++mi)
            #pragma unroll
            for (int ni = 0; ni < 5; ++ni)
                acc2[mi][ni] = __builtin_amdgcn_mfma_f32_16x16x32_bf16(
                    af[mi], bf[ni], acc2[mi][ni], 0, 0, 0);
        __syncthreads();
        cur2 ^= 1;
    }

    // ---------------- epilogue: bias+relu, per-row LN, write out ------------
    float vals[2][5][4];
    float rsum[2][4] = {}, rsq[2][4] = {};
    #pragma unroll
    for (int ni = 0; ni < 5; ++ni) {
        int col = wn * 80 + ni * 16 + fr;
        float bv = (col < H2_) ? b2[col] : 0.f;
        #pragma unroll
        for (int mi = 0; mi < 2; ++mi)
            #pragma unroll
            for (int j = 0; j < 4; ++j) {
                float v = acc2[mi][ni][j] + bv;
                v = v > 0.f ? v : 0.f;
                vals[mi][ni][j] = v;
                rsum[mi][j] += v;
                rsq[mi][j]  += v * v;
            }
    }
    #pragma unroll
    for (int off = 1; off < 16; off <<= 1)
        #pragma unroll
        for (int mi = 0; mi < 2; ++mi)
            #pragma unroll
            for (int j = 0; j < 4; ++j) {
                rsum[mi][j] += __shfl_xor(rsum[mi][j], off);
                rsq[mi][j]  += __shfl_xor(rsq[mi][j], off);
            }
    if (fr == 0) {
        #pragma unroll
        for (int mi = 0; mi < 2; ++mi)
            #pragma unroll
            for (int j = 0; j < 4; ++j) {
                int r32 = mi * 16 + g * 4 + j;
                red[wm][r32][wn][0] = rsum[mi][j];
                red[wm][r32][wn][1] = rsq[mi][j];
            }
    }
    __syncthreads();
    #pragma unroll
    for (int mi = 0; mi < 2; ++mi) {
        #pragma unroll
        for (int j = 0; j < 4; ++j) {
            int r32 = mi * 16 + g * 4 + j;
            float S  = red[wm][r32][0][0] + red[wm][r32][1][0]
                     + red[wm][r32][2][0] + red[wm][r32][3][0];
            float SQ = red[wm][r32][0][1] + red[wm][r32][1][1]
                     + red[wm][r32][2][1] + red[wm][r32][3][1];
            float mu   = S * (1.0f / H2_);
            float var  = SQ * (1.0f / H2_) - mu * mu;
            float rstd = rsqrtf(var + LN_EPS);
            int row = bm + wm * 32 + r32;
            #pragma unroll
            for (int ni = 0; ni < 5; ++ni) {
                int col = wn * 80 + ni * 16 + fr;
                if (col < H2_)
                    out[(size_t)row * H2_ + col] =
                        (vals[mi][ni][j] - mu) * rstd * gamma[col] + beta[col];
            }
        }
    }
}

// ----------------------------------------------------------------- launch ---
extern "C" void kernel_launch(void* const* d_in, const int* in_sizes, int n_in,
                              void* d_out, int out_size, void* d_ws, size_t ws_size,
                              hipStream_t stream)
{
    const float* texts  = (const float*)d_in[0];
    const int*   wstart = (const int*)  d_in[1];
    const int*   wend   = (const int*)  d_in[2];
    const int*   wlen   = (const int*)  d_in[3];
    const float* W1     = (const float*)d_in[4];
    const float* b1     = (const float*)d_in[5];
    const float* W2     = (const float*)d_in[6];
    const float* b2     = (const float*)d_in[7];
    const float* gamma  = (const float*)d_in[8];
    const float* beta   = (const float*)d_in[9];
    float* out = (float*)d_out;

    ushort* pooled = (ushort*)d_ws;                 // M x 768 bf16
    ushort* W1T    = pooled + (size_t)M_ * D_;      // 512 x 768 bf16
    ushort* W2T    = W1T + (size_t)H1P * D_;        // 320 x 512 bf16

    prep_kernel<<<M_ + CONV1_B + CONV2_B, 192, 0, stream>>>(
        texts, wstart, wend, wlen, W1, W2,
        (__hip_bfloat16*)pooled, (__hip_bfloat16*)W1T, (__hip_bfloat16*)W2T);

    mlp_ln_kernel<<<M_ / 64, 512, 0, stream>>>(
        pooled, W1T, W2T, b1, b2, gamma, beta, out);
}

// Round 5
// 63.142 us; speedup vs baseline: 1.1751x; 1.1751x over previous
//
#include <hip/hip_runtime.h>
#include <hip/hip_bf16.h>

// TextEncoder: segment-mean pool -> relu(x@W1+b1) -> relu(h@W2+b2) -> LayerNorm
// R5: back to 3 kernels (R4 mega-fusion was latency-bound at 1 block/CU).
// Both GEMMs now use the T4 counted-vmcnt pipeline: 4 LDS buffers, loads for
// 3 K-steps in flight, ONE raw s_barrier per step, vmcnt never drained to 0
// in the main loop (only in the 2 peeled tail steps). T5 setprio around MFMA.
//
// Padding: W1T=[512][768] (rows>=500 zero) -> h1 pad cols = relu(0)=0;
// W2T=[320][512] (k>=500, n>=300 zero) -> pad out cols = 0, excluded from LN.

#define N_  64
#define L_  514
#define D_  768
#define W_  256
#define H1_ 500
#define H1P 512
#define H2_ 300
#define H2P 320
#define LN_EPS 1e-5f
#define M_  (N_ * W_)   // 16384

typedef __bf16 bf16x8 __attribute__((ext_vector_type(8)));
typedef float  f32x4  __attribute__((ext_vector_type(4)));

__device__ __forceinline__ void load_lds16(const void* g, void* l) {
    __builtin_amdgcn_global_load_lds(
        (const __attribute__((address_space(1))) void*)g,
        (__attribute__((address_space(3))) void*)l, 16, 0, 0);
}

// ------------------------------------------------------------------ prep ---
#define CONV1_ELEMS (H1P * D_)     // 393216
#define CONV2_ELEMS (H2P * H1P)    // 163840
#define CONV1_B ((CONV1_ELEMS + 191) / 192)   // 2048
#define CONV2_B ((CONV2_ELEMS + 191) / 192)   // 854

__global__ __launch_bounds__(192) void prep_kernel(
    const float* __restrict__ texts, const int* __restrict__ wstart,
    const int* __restrict__ wend, const int* __restrict__ wlen,
    const float* __restrict__ W1, const float* __restrict__ W2,
    __hip_bfloat16* __restrict__ pooled, __hip_bfloat16* __restrict__ W1T,
    __hip_bfloat16* __restrict__ W2T)
{
    int b = blockIdx.x;
    if (b < M_) {
        int n = b >> 8;
        int w = b & (W_ - 1);
        int s = wstart[b], e = wend[b];
        bool live = (w < wlen[n]);
        int d = threadIdx.x * 4;
        float4 acc = make_float4(0.f, 0.f, 0.f, 0.f);
        if (live) {
            const float* base = texts + ((size_t)n * L_ + 1) * D_ + d;  // tok=texts[:,1:-1]
            for (int i = s; i < e; ++i) {
                float4 v = *reinterpret_cast<const float4*>(base + (size_t)i * D_);
                acc.x += v.x; acc.y += v.y; acc.z += v.z; acc.w += v.w;
            }
            float inv = 1.0f / (float)max(e - s, 1);
            acc.x *= inv; acc.y *= inv; acc.z *= inv; acc.w *= inv;
        }
        union { __hip_bfloat16 h[4]; uint2 u; } o;
        o.h[0] = __float2bfloat16(acc.x); o.h[1] = __float2bfloat16(acc.y);
        o.h[2] = __float2bfloat16(acc.z); o.h[3] = __float2bfloat16(acc.w);
        *reinterpret_cast<uint2*>(pooled + (size_t)b * D_ + d) = o.u;
    } else if (b < M_ + CONV1_B) {
        int t = (b - M_) * 192 + threadIdx.x;
        if (t < CONV1_ELEMS) {
            int n = t / D_, k = t - n * D_;
            float v = (n < H1_) ? W1[(size_t)k * H1_ + n] : 0.f;
            W1T[t] = __float2bfloat16(v);
        }
    } else {
        int t = (b - M_ - CONV1_B) * 192 + threadIdx.x;
        if (t < CONV2_ELEMS) {
            int n = t >> 9, k = t & (H1P - 1);
            float v = (n < H2_ && k < H1_) ? W2[(size_t)k * H2_ + n] : 0.f;
            W2T[t] = __float2bfloat16(v);
        }
    }
}

// --------------------------------------------------------- GEMM1 (MFMA) ----
// h1[16384 x 512] = relu(pooled[16384 x 768] @ W1T^T + b1). 128x128 tile,
// 4 waves (2x2), FM=FN=4 (16 MFMA : 8 ds_read_b128 per K-step, m97 ratio).
// 4-buffer counted-vmcnt pipeline; 64 KB LDS -> 2 blocks/CU.
__global__ __launch_bounds__(256, 2) void gemm1_kernel(
    const ushort* __restrict__ A, const ushort* __restrict__ B,
    const float* __restrict__ b1, ushort* __restrict__ h1)
{
    constexpr int BUFB = 16384;                 // (128+128) rows * 64 B
    __shared__ __align__(16) char bufs[4 * BUFB];
    const int tid  = threadIdx.x;
    const int wave = tid >> 6, lane = tid & 63;
    const int wm = wave >> 1, wn = wave & 1;    // 2 x 2
    const int bm = blockIdx.y * 128, bn = blockIdx.x * 128;
    const int lrow = lane >> 2, lslot = lane & 3;
    const int g = lane >> 4, fr = lane & 15;

    f32x4 acc[4][4] = {};

    // 16 chunks (8 A + 8 B) of 16 rows x 64 B; 4 per wave. Linear LDS dest +
    // XOR-swizzled global source (rule #21); swizzle = ((row>>1)&3) on 16B slot.
    auto stage = [&](int buf, int kt) {
        char* base = bufs + buf * BUFB;
        #pragma unroll
        for (int c0 = 0; c0 < 4; ++c0) {
            int c = wave + c0 * 4;              // 0..15
            int row = (c & 7) * 16 + lrow;
            const ushort* src = (c < 8) ? A + (size_t)(bm + row) * D_
                                        : B + (size_t)(bn + row) * D_;
            int sslot = lslot ^ ((row >> 1) & 3);
            load_lds16(src + kt + sslot * 8, base + c * 1024);
        }
    };

    auto compute = [&](int t) {
        const char* base = bufs + (t & 3) * BUFB;
        bf16x8 af[4], bf[4];
        #pragma unroll
        for (int mi = 0; mi < 4; ++mi) {
            int r = wm * 64 + mi * 16 + fr;
            af[mi] = *(const bf16x8*)(base + r * 64 + ((g ^ ((r >> 1) & 3)) << 4));
        }
        #pragma unroll
        for (int ni = 0; ni < 4; ++ni) {
            int r = wn * 64 + ni * 16 + fr;
            bf[ni] = *(const bf16x8*)(base + 8192 + r * 64 + ((g ^ ((r >> 1) & 3)) << 4));
        }
        __builtin_amdgcn_s_setprio(1);
        #pragma unroll
        for (int mi = 0; mi < 4; ++mi)
            #pragma unroll
            for (int ni = 0; ni < 4; ++ni)
                acc[mi][ni] = __builtin_amdgcn_mfma_f32_16x16x32_bf16(
                    af[mi], bf[ni], acc[mi][ni], 0, 0, 0);
        __builtin_amdgcn_s_setprio(0);
    };

    // pipeline: K=768 -> NT=24 steps; 3 stages (12 loads/wave) in flight.
    stage(0, 0); stage(1, 32); stage(2, 64);
    for (int t = 0; t < 22; ++t) {
        asm volatile("s_waitcnt vmcnt(8)" ::: "memory");   // stage t complete
        __builtin_amdgcn_s_barrier();
        if (t + 3 < 24) stage((t + 3) & 3, (t + 3) * 32);
        compute(t);
    }
    asm volatile("s_waitcnt vmcnt(4)" ::: "memory");
    __builtin_amdgcn_s_barrier();
    compute(22);
    asm volatile("s_waitcnt vmcnt(0)" ::: "memory");
    __builtin_amdgcn_s_barrier();
    compute(23);

    // epilogue: relu(acc + b1) -> bf16 h1 [M][512]; pad cols (>=500) get 0.
    #pragma unroll
    for (int mi = 0; mi < 4; ++mi)
        #pragma unroll
        for (int ni = 0; ni < 4; ++ni) {
            int col = bn + wn * 64 + ni * 16 + fr;
            float bv = (col < H1_) ? b1[col] : 0.f;
            #pragma unroll
            for (int j = 0; j < 4; ++j) {
                int row = bm + wm * 64 + mi * 16 + g * 4 + j;
                float v = acc[mi][ni][j] + bv;
                ((__hip_bfloat16*)h1)[(size_t)row * H1P + col] =
                    __float2bfloat16(v > 0.f ? v : 0.f);
            }
        }
}

// ------------------------------------------- GEMM2 + bias + relu + LN ------
// out[16384 x 300] = LN(relu(h1 @ W2T^T + b2)). BM=64, BN=320 (full row so LN
// fuses), K=512 -> 16 steps. 8 waves (2x4), wave tile 32x80 (FM=2, FN=5).
// Same counted-vmcnt 4-buffer pipeline (3 loads/wave/stage -> vmcnt 6/3/0).
__global__ __launch_bounds__(512, 1) void gemm2_ln_kernel(
    const ushort* __restrict__ A, const ushort* __restrict__ B,
    const float* __restrict__ b2, const float* __restrict__ gamma,
    const float* __restrict__ beta, float* __restrict__ out)
{
    constexpr int BUFB = 24576;                 // (64+320) rows * 64 B
    __shared__ __align__(16) char bufs[4 * BUFB];   // 96 KB
    __shared__ float red[2][32][4][2];          // [wm][row][wn][sum|sq]
    const int tid  = threadIdx.x;
    const int wave = tid >> 6, lane = tid & 63;
    const int wm = wave >> 2, wn = wave & 3;    // 2 x 4
    const int bm = blockIdx.x * 64;
    const int lrow = lane >> 2, lslot = lane & 3;
    const int g = lane >> 4, fr = lane & 15;

    f32x4 acc[2][5] = {};

    // 24 chunks (4 A + 20 B), 3 per wave.
    auto stage = [&](int buf, int kt) {
        char* base = bufs + buf * BUFB;
        #pragma unroll
        for (int c0 = 0; c0 < 3; ++c0) {
            int c = wave + c0 * 8;              // 0..23
            int row; const ushort* src;
            if (c < 4) { row = c * 16 + lrow; src = A + (size_t)(bm + row) * H1P; }
            else       { row = (c - 4) * 16 + lrow; src = B + (size_t)row * H1P; }
            int sslot = lslot ^ ((row >> 1) & 3);
            load_lds16(src + kt + sslot * 8, base + c * 1024);
        }
    };

    auto compute = [&](int t) {
        const char* base = bufs + (t & 3) * BUFB;
        bf16x8 af[2], bf[5];
        #pragma unroll
        for (int mi = 0; mi < 2; ++mi) {
            int r = wm * 32 + mi * 16 + fr;
            af[mi] = *(const bf16x8*)(base + r * 64 + ((g ^ ((r >> 1) & 3)) << 4));
        }
        #pragma unroll
        for (int ni = 0; ni < 5; ++ni) {
            int r = wn * 80 + ni * 16 + fr;
            bf[ni] = *(const bf16x8*)(base + 4096 + r * 64 + ((g ^ ((r >> 1) & 3)) << 4));
        }
        __builtin_amdgcn_s_setprio(1);
        #pragma unroll
        for (int mi = 0; mi < 2; ++mi)
            #pragma unroll
            for (int ni = 0; ni < 5; ++ni)
                acc[mi][ni] = __builtin_amdgcn_mfma_f32_16x16x32_bf16(
                    af[mi], bf[ni], acc[mi][ni], 0, 0, 0);
        __builtin_amdgcn_s_setprio(0);
    };

    stage(0, 0); stage(1, 32); stage(2, 64);
    for (int t = 0; t < 14; ++t) {
        asm volatile("s_waitcnt vmcnt(6)" ::: "memory");
        __builtin_amdgcn_s_barrier();
        if (t + 3 < 16) stage((t + 3) & 3, (t + 3) * 32);
        compute(t);
    }
    asm volatile("s_waitcnt vmcnt(3)" ::: "memory");
    __builtin_amdgcn_s_barrier();
    compute(14);
    asm volatile("s_waitcnt vmcnt(0)" ::: "memory");
    __builtin_amdgcn_s_barrier();
    compute(15);

    // ---- epilogue: bias+relu in regs, per-row mean/var, normalize, write ----
    float vals[2][5][4];
    float rsum[2][4] = {}, rsq[2][4] = {};
    #pragma unroll
    for (int ni = 0; ni < 5; ++ni) {
        int col = wn * 80 + ni * 16 + fr;
        float bv = (col < H2_) ? b2[col] : 0.f;
        #pragma unroll
        for (int mi = 0; mi < 2; ++mi)
            #pragma unroll
            for (int j = 0; j < 4; ++j) {
                float v = acc[mi][ni][j] + bv;
                v = v > 0.f ? v : 0.f;
                vals[mi][ni][j] = v;
                rsum[mi][j] += v;
                rsq[mi][j]  += v * v;
            }
    }
    #pragma unroll
    for (int off = 1; off < 16; off <<= 1)
        #pragma unroll
        for (int mi = 0; mi < 2; ++mi)
            #pragma unroll
            for (int j = 0; j < 4; ++j) {
                rsum[mi][j] += __shfl_xor(rsum[mi][j], off);
                rsq[mi][j]  += __shfl_xor(rsq[mi][j], off);
            }
    if (fr == 0) {
        #pragma unroll
        for (int mi = 0; mi < 2; ++mi)
            #pragma unroll
            for (int j = 0; j < 4; ++j) {
                int r32 = mi * 16 + g * 4 + j;
                red[wm][r32][wn][0] = rsum[mi][j];
                red[wm][r32][wn][1] = rsq[mi][j];
            }
    }
    __syncthreads();
    #pragma unroll
    for (int mi = 0; mi < 2; ++mi) {
        #pragma unroll
        for (int j = 0; j < 4; ++j) {
            int r32 = mi * 16 + g * 4 + j;
            float S  = red[wm][r32][0][0] + red[wm][r32][1][0]
                     + red[wm][r32][2][0] + red[wm][r32][3][0];
            float SQ = red[wm][r32][0][1] + red[wm][r32][1][1]
                     + red[wm][r32][2][1] + red[wm][r32][3][1];
            float mu   = S * (1.0f / H2_);
            float var  = SQ * (1.0f / H2_) - mu * mu;
            float rstd = rsqrtf(var + LN_EPS);
            int row = bm + wm * 32 + r32;
            #pragma unroll
            for (int ni = 0; ni < 5; ++ni) {
                int col = wn * 80 + ni * 16 + fr;
                if (col < H2_)
                    out[(size_t)row * H2_ + col] =
                        (vals[mi][ni][j] - mu) * rstd * gamma[col] + beta[col];
            }
        }
    }
}

// ----------------------------------------------------------------- launch ---
extern "C" void kernel_launch(void* const* d_in, const int* in_sizes, int n_in,
                              void* d_out, int out_size, void* d_ws, size_t ws_size,
                              hipStream_t stream)
{
    const float* texts  = (const float*)d_in[0];
    const int*   wstart = (const int*)  d_in[1];
    const int*   wend   = (const int*)  d_in[2];
    const int*   wlen   = (const int*)  d_in[3];
    const float* W1     = (const float*)d_in[4];
    const float* b1     = (const float*)d_in[5];
    const float* W2     = (const float*)d_in[6];
    const float* b2     = (const float*)d_in[7];
    const float* gamma  = (const float*)d_in[8];
    const float* beta   = (const float*)d_in[9];
    float* out = (float*)d_out;

    ushort* pooled = (ushort*)d_ws;                 // M x 768 bf16
    ushort* h1     = pooled + (size_t)M_ * D_;      // M x 512 bf16
    ushort* W1T    = h1 + (size_t)M_ * H1P;         // 512 x 768 bf16
    ushort* W2T    = W1T + (size_t)H1P * D_;        // 320 x 512 bf16

    prep_kernel<<<M_ + CONV1_B + CONV2_B, 192, 0, stream>>>(
        texts, wstart, wend, wlen, W1, W2,
        (__hip_bfloat16*)pooled, (__hip_bfloat16*)W1T, (__hip_bfloat16*)W2T);

    dim3 g1(H1P / 128, M_ / 128);   // 4 x 128 = 512 blocks
    gemm1_kernel<<<g1, 256, 0, stream>>>(pooled, W1T, b1, h1);

    gemm2_ln_kernel<<<M_ / 64, 512, 0, stream>>>(h1, W2T, b2, gamma, beta, out);
}

// Round 6
// 57.097 us; speedup vs baseline: 1.2995x; 1.1059x over previous
//
#include <hip/hip_runtime.h>
#include <hip/hip_bf16.h>

// TextEncoder: segment-mean pool -> relu(x@W1+b1) -> relu(h@W2+b2) -> LayerNorm
// R6: gemm1 re-tiled BM=256 x BN=128 (staged bytes/CU -25%) + m204 XCD swizzle
// (same-bm quads co-XCD -> A-staging L2 hits). Counted-vmcnt depth-3 pipeline
// kept in both GEMMs; prep and gemm2_ln unchanged from R5.
//
// Padding: W1T=[512][768] (rows>=500 zero) -> h1 pad cols = relu(0)=0;
// W2T=[320][512] (k>=500, n>=300 zero) -> pad out cols = 0, excluded from LN.

#define N_  64
#define L_  514
#define D_  768
#define W_  256
#define H1_ 500
#define H1P 512
#define H2_ 300
#define H2P 320
#define LN_EPS 1e-5f
#define M_  (N_ * W_)   // 16384

typedef __bf16 bf16x8 __attribute__((ext_vector_type(8)));
typedef float  f32x4  __attribute__((ext_vector_type(4)));

__device__ __forceinline__ void load_lds16(const void* g, void* l) {
    __builtin_amdgcn_global_load_lds(
        (const __attribute__((address_space(1))) void*)g,
        (__attribute__((address_space(3))) void*)l, 16, 0, 0);
}

// ------------------------------------------------------------------ prep ---
#define CONV1_ELEMS (H1P * D_)     // 393216
#define CONV2_ELEMS (H2P * H1P)    // 163840
#define CONV1_B ((CONV1_ELEMS + 191) / 192)   // 2048
#define CONV2_B ((CONV2_ELEMS + 191) / 192)   // 854

__global__ __launch_bounds__(192) void prep_kernel(
    const float* __restrict__ texts, const int* __restrict__ wstart,
    const int* __restrict__ wend, const int* __restrict__ wlen,
    const float* __restrict__ W1, const float* __restrict__ W2,
    __hip_bfloat16* __restrict__ pooled, __hip_bfloat16* __restrict__ W1T,
    __hip_bfloat16* __restrict__ W2T)
{
    int b = blockIdx.x;
    if (b < M_) {
        int n = b >> 8;
        int w = b & (W_ - 1);
        int s = wstart[b], e = wend[b];
        bool live = (w < wlen[n]);
        int d = threadIdx.x * 4;
        float4 acc = make_float4(0.f, 0.f, 0.f, 0.f);
        if (live) {
            const float* base = texts + ((size_t)n * L_ + 1) * D_ + d;  // tok=texts[:,1:-1]
            for (int i = s; i < e; ++i) {
                float4 v = *reinterpret_cast<const float4*>(base + (size_t)i * D_);
                acc.x += v.x; acc.y += v.y; acc.z += v.z; acc.w += v.w;
            }
            float inv = 1.0f / (float)max(e - s, 1);
            acc.x *= inv; acc.y *= inv; acc.z *= inv; acc.w *= inv;
        }
        union { __hip_bfloat16 h[4]; uint2 u; } o;
        o.h[0] = __float2bfloat16(acc.x); o.h[1] = __float2bfloat16(acc.y);
        o.h[2] = __float2bfloat16(acc.z); o.h[3] = __float2bfloat16(acc.w);
        *reinterpret_cast<uint2*>(pooled + (size_t)b * D_ + d) = o.u;
    } else if (b < M_ + CONV1_B) {
        int t = (b - M_) * 192 + threadIdx.x;
        if (t < CONV1_ELEMS) {
            int n = t / D_, k = t - n * D_;
            float v = (n < H1_) ? W1[(size_t)k * H1_ + n] : 0.f;
            W1T[t] = __float2bfloat16(v);
        }
    } else {
        int t = (b - M_ - CONV1_B) * 192 + threadIdx.x;
        if (t < CONV2_ELEMS) {
            int n = t >> 9, k = t & (H1P - 1);
            float v = (n < H2_ && k < H1_) ? W2[(size_t)k * H2_ + n] : 0.f;
            W2T[t] = __float2bfloat16(v);
        }
    }
}

// --------------------------------------------------------- GEMM1 (MFMA) ----
// h1[16384 x 512] = relu(pooled @ W1T^T + b1). BM=256, BN=128, 8 waves (4x2),
// wave tile 64x64 (FM=FN=4). Grid = 256 blocks = 1/CU; staged bytes/CU =
// 24 steps x 24KB = 576KB (was 768KB at 128^2 x 2 blocks). m204 XCD swizzle:
// the 4 bn-blocks of one bm land on one XCD -> A re-reads are L2 hits.
// 4-buffer counted-vmcnt pipeline (3 loads/wave/stage -> vmcnt 6/3/0).
__global__ __launch_bounds__(512, 1) void gemm1_kernel(
    const ushort* __restrict__ A, const ushort* __restrict__ B,
    const float* __restrict__ b1, ushort* __restrict__ h1)
{
    constexpr int BUFB = 24576;                 // (256+128) rows * 64 B
    __shared__ __align__(16) char bufs[4 * BUFB];   // 96 KB
    const int tid  = threadIdx.x;
    const int wave = tid >> 6, lane = tid & 63;
    const int wm = wave >> 1, wn = wave & 1;    // 4 x 2
    // XCD swizzle (nwg=256 divisible by 8): tile = (b%8)*32 + b/8.
    // Same-XCD chunk = 32 consecutive tiles = 8 bm-quads (each quad shares A).
    const int t256 = (blockIdx.x & 7) * 32 + (blockIdx.x >> 3);
    const int bm = (t256 >> 2) * 256, bn = (t256 & 3) * 128;
    const int lrow = lane >> 2, lslot = lane & 3;
    const int g = lane >> 4, fr = lane & 15;

    f32x4 acc[4][4] = {};

    // 24 chunks (16 A + 8 B) of 16 rows x 64 B; 3 per wave. Linear LDS dest +
    // XOR-swizzled global source (rule #21); swizzle = ((row>>1)&3) on 16B slot.
    auto stage = [&](int buf, int kt) {
        char* base = bufs + buf * BUFB;
        #pragma unroll
        for (int c0 = 0; c0 < 3; ++c0) {
            int c = wave + c0 * 8;              // 0..23
            int row; const ushort* src;
            if (c < 16) { row = c * 16 + lrow; src = A + (size_t)(bm + row) * D_; }
            else        { row = (c - 16) * 16 + lrow; src = B + (size_t)(bn + row) * D_; }
            int sslot = lslot ^ ((row >> 1) & 3);
            load_lds16(src + kt + sslot * 8, base + c * 1024);
        }
    };

    auto compute = [&](int t) {
        const char* base = bufs + (t & 3) * BUFB;
        bf16x8 af[4], bf[4];
        #pragma unroll
        for (int mi = 0; mi < 4; ++mi) {
            int r = wm * 64 + mi * 16 + fr;
            af[mi] = *(const bf16x8*)(base + r * 64 + ((g ^ ((r >> 1) & 3)) << 4));
        }
        #pragma unroll
        for (int ni = 0; ni < 4; ++ni) {
            int r = wn * 64 + ni * 16 + fr;
            bf[ni] = *(const bf16x8*)(base + 16384 + r * 64 + ((g ^ ((r >> 1) & 3)) << 4));
        }
        __builtin_amdgcn_s_setprio(1);
        #pragma unroll
        for (int mi = 0; mi < 4; ++mi)
            #pragma unroll
            for (int ni = 0; ni < 4; ++ni)
                acc[mi][ni] = __builtin_amdgcn_mfma_f32_16x16x32_bf16(
                    af[mi], bf[ni], acc[mi][ni], 0, 0, 0);
        __builtin_amdgcn_s_setprio(0);
    };

    // pipeline: K=768 -> 24 steps; 3 stages (9 loads/wave) in flight.
    stage(0, 0); stage(1, 32); stage(2, 64);
    for (int t = 0; t < 22; ++t) {
        asm volatile("s_waitcnt vmcnt(6)" ::: "memory");   // stage t complete
        __builtin_amdgcn_s_barrier();
        if (t + 3 < 24) stage((t + 3) & 3, (t + 3) * 32);
        compute(t);
    }
    asm volatile("s_waitcnt vmcnt(3)" ::: "memory");
    __builtin_amdgcn_s_barrier();
    compute(22);
    asm volatile("s_waitcnt vmcnt(0)" ::: "memory");
    __builtin_amdgcn_s_barrier();
    compute(23);

    // epilogue: relu(acc + b1) -> bf16 h1 [M][512]; pad cols (>=500) get 0.
    #pragma unroll
    for (int mi = 0; mi < 4; ++mi)
        #pragma unroll
        for (int ni = 0; ni < 4; ++ni) {
            int col = bn + wn * 64 + ni * 16 + fr;
            float bv = (col < H1_) ? b1[col] : 0.f;
            #pragma unroll
            for (int j = 0; j < 4; ++j) {
                int row = bm + wm * 64 + mi * 16 + g * 4 + j;
                float v = acc[mi][ni][j] + bv;
                ((__hip_bfloat16*)h1)[(size_t)row * H1P + col] =
                    __float2bfloat16(v > 0.f ? v : 0.f);
            }
        }
}

// ------------------------------------------- GEMM2 + bias + relu + LN ------
// out[16384 x 300] = LN(relu(h1 @ W2T^T + b2)). BM=64, BN=320 (full row so LN
// fuses), K=512 -> 16 steps. 8 waves (2x4), wave tile 32x80 (FM=2, FN=5).
// Counted-vmcnt 4-buffer pipeline (3 loads/wave/stage -> vmcnt 6/3/0).
__global__ __launch_bounds__(512, 1) void gemm2_ln_kernel(
    const ushort* __restrict__ A, const ushort* __restrict__ B,
    const float* __restrict__ b2, const float* __restrict__ gamma,
    const float* __restrict__ beta, float* __restrict__ out)
{
    constexpr int BUFB = 24576;                 // (64+320) rows * 64 B
    __shared__ __align__(16) char bufs[4 * BUFB];   // 96 KB
    __shared__ float red[2][32][4][2];          // [wm][row][wn][sum|sq]
    const int tid  = threadIdx.x;
    const int wave = tid >> 6, lane = tid & 63;
    const int wm = wave >> 2, wn = wave & 3;    // 2 x 4
    const int bm = blockIdx.x * 64;
    const int lrow = lane >> 2, lslot = lane & 3;
    const int g = lane >> 4, fr = lane & 15;

    f32x4 acc[2][5] = {};

    // 24 chunks (4 A + 20 B), 3 per wave.
    auto stage = [&](int buf, int kt) {
        char* base = bufs + buf * BUFB;
        #pragma unroll
        for (int c0 = 0; c0 < 3; ++c0) {
            int c = wave + c0 * 8;              // 0..23
            int row; const ushort* src;
            if (c < 4) { row = c * 16 + lrow; src = A + (size_t)(bm + row) * H1P; }
            else       { row = (c - 4) * 16 + lrow; src = B + (size_t)row * H1P; }
            int sslot = lslot ^ ((row >> 1) & 3);
            load_lds16(src + kt + sslot * 8, base + c * 1024);
        }
    };

    auto compute = [&](int t) {
        const char* base = bufs + (t & 3) * BUFB;
        bf16x8 af[2], bf[5];
        #pragma unroll
        for (int mi = 0; mi < 2; ++mi) {
            int r = wm * 32 + mi * 16 + fr;
            af[mi] = *(const bf16x8*)(base + r * 64 + ((g ^ ((r >> 1) & 3)) << 4));
        }
        #pragma unroll
        for (int ni = 0; ni < 5; ++ni) {
            int r = wn * 80 + ni * 16 + fr;
            bf[ni] = *(const bf16x8*)(base + 4096 + r * 64 + ((g ^ ((r >> 1) & 3)) << 4));
        }
        __builtin_amdgcn_s_setprio(1);
        #pragma unroll
        for (int mi = 0; mi < 2; ++mi)
            #pragma unroll
            for (int ni = 0; ni < 5; ++ni)
                acc[mi][ni] = __builtin_amdgcn_mfma_f32_16x16x32_bf16(
                    af[mi], bf[ni], acc[mi][ni], 0, 0, 0);
        __builtin_amdgcn_s_setprio(0);
    };

    stage(0, 0); stage(1, 32); stage(2, 64);
    for (int t = 0; t < 14; ++t) {
        asm volatile("s_waitcnt vmcnt(6)" ::: "memory");
        __builtin_amdgcn_s_barrier();
        if (t + 3 < 16) stage((t + 3) & 3, (t + 3) * 32);
        compute(t);
    }
    asm volatile("s_waitcnt vmcnt(3)" ::: "memory");
    __builtin_amdgcn_s_barrier();
    compute(14);
    asm volatile("s_waitcnt vmcnt(0)" ::: "memory");
    __builtin_amdgcn_s_barrier();
    compute(15);

    // ---- epilogue: bias+relu in regs, per-row mean/var, normalize, write ----
    float vals[2][5][4];
    float rsum[2][4] = {}, rsq[2][4] = {};
    #pragma unroll
    for (int ni = 0; ni < 5; ++ni) {
        int col = wn * 80 + ni * 16 + fr;
        float bv = (col < H2_) ? b2[col] : 0.f;
        #pragma unroll
        for (int mi = 0; mi < 2; ++mi)
            #pragma unroll
            for (int j = 0; j < 4; ++j) {
                float v = acc[mi][ni][j] + bv;
                v = v > 0.f ? v : 0.f;
                vals[mi][ni][j] = v;
                rsum[mi][j] += v;
                rsq[mi][j]  += v * v;
            }
    }
    #pragma unroll
    for (int off = 1; off < 16; off <<= 1)
        #pragma unroll
        for (int mi = 0; mi < 2; ++mi)
            #pragma unroll
            for (int j = 0; j < 4; ++j) {
                rsum[mi][j] += __shfl_xor(rsum[mi][j], off);
                rsq[mi][j]  += __shfl_xor(rsq[mi][j], off);
            }
    if (fr == 0) {
        #pragma unroll
        for (int mi = 0; mi < 2; ++mi)
            #pragma unroll
            for (int j = 0; j < 4; ++j) {
                int r32 = mi * 16 + g * 4 + j;
                red[wm][r32][wn][0] = rsum[mi][j];
                red[wm][r32][wn][1] = rsq[mi][j];
            }
    }
    __syncthreads();
    #pragma unroll
    for (int mi = 0; mi < 2; ++mi) {
        #pragma unroll
        for (int j = 0; j < 4; ++j) {
            int r32 = mi * 16 + g * 4 + j;
            float S  = red[wm][r32][0][0] + red[wm][r32][1][0]
                     + red[wm][r32][2][0] + red[wm][r32][3][0];
            float SQ = red[wm][r32][0][1] + red[wm][r32][1][1]
                     + red[wm][r32][2][1] + red[wm][r32][3][1];
            float mu   = S * (1.0f / H2_);
            float var  = SQ * (1.0f / H2_) - mu * mu;
            float rstd = rsqrtf(var + LN_EPS);
            int row = bm + wm * 32 + r32;
            #pragma unroll
            for (int ni = 0; ni < 5; ++ni) {
                int col = wn * 80 + ni * 16 + fr;
                if (col < H2_)
                    out[(size_t)row * H2_ + col] =
                        (vals[mi][ni][j] - mu) * rstd * gamma[col] + beta[col];
            }
        }
    }
}

// ----------------------------------------------------------------- launch ---
extern "C" void kernel_launch(void* const* d_in, const int* in_sizes, int n_in,
                              void* d_out, int out_size, void* d_ws, size_t ws_size,
                              hipStream_t stream)
{
    const float* texts  = (const float*)d_in[0];
    const int*   wstart = (const int*)  d_in[1];
    const int*   wend   = (const int*)  d_in[2];
    const int*   wlen   = (const int*)  d_in[3];
    const float* W1     = (const float*)d_in[4];
    const float* b1     = (const float*)d_in[5];
    const float* W2     = (const float*)d_in[6];
    const float* b2     = (const float*)d_in[7];
    const float* gamma  = (const float*)d_in[8];
    const float* beta   = (const float*)d_in[9];
    float* out = (float*)d_out;

    ushort* pooled = (ushort*)d_ws;                 // M x 768 bf16
    ushort* h1     = pooled + (size_t)M_ * D_;      // M x 512 bf16
    ushort* W1T    = h1 + (size_t)M_ * H1P;         // 512 x 768 bf16
    ushort* W2T    = W1T + (size_t)H1P * D_;        // 320 x 512 bf16

    prep_kernel<<<M_ + CONV1_B + CONV2_B, 192, 0, stream>>>(
        texts, wstart, wend, wlen, W1, W2,
        (__hip_bfloat16*)pooled, (__hip_bfloat16*)W1T, (__hip_bfloat16*)W2T);

    gemm1_kernel<<<256, 512, 0, stream>>>(pooled, W1T, b1, h1);

    gemm2_ln_kernel<<<M_ / 64, 512, 0, stream>>>(h1, W2T, b2, gamma, beta, out);
}